// Round 19
// baseline (544.871 us; speedup 1.0000x reference)
//
#include <hip/hip_runtime.h>
#include <cstdint>

#define B_ 4
#define H_ 16
#define S_ 2048
#define D_ 64

// fold temperature (1/8) and log2(e) into q so exp(x) == exp2(scaled dot)
#define QSCALE (0.125f * 1.44269504088896f)

typedef _Float16 half8 __attribute__((ext_vector_type(8)));
typedef float f32x4 __attribute__((ext_vector_type(4)));
typedef float f32x16 __attribute__((ext_vector_type(16)));
typedef uint32_t u32x2 __attribute__((ext_vector_type(2)));
typedef uint32_t u32x4 __attribute__((ext_vector_type(4)));

// ---------- fused pre-kernel ----------
// grid (64, 80): y<64 -> q-cvt + K-pack + V-pack for (bh=y, tile=x);
//                y>=64 -> mask bitmap slice (16 slices x 512 q-rows).
// K fragment layout: half8 slot [((bh*64+t)*4+kk)*64 + hi*32 + c]
// V fragment layout: half8 slot [((bh*64+t)*8 + g)*32 + c], g=kk*4+hi*2+db
// mask query-tile-major: word [((b*64 + q/32)*64 + t)*32 + q%32]

__global__ __launch_bounds__(256) void pack_all(
    const float* __restrict__ q, const float* __restrict__ k, const float* __restrict__ v,
    const int* __restrict__ mask,
    _Float16* __restrict__ qh, _Float16* __restrict__ kh, _Float16* __restrict__ vt,
    uint32_t* __restrict__ mbT)
{
    const int t = blockIdx.x;        // 0..63
    const int y = blockIdx.y;        // 0..79
    const int tid = threadIdx.x;

    if (y < 64) {
        const int bh = y;
        // ---- q convert (contiguous, 8 f32 per thread) ----
        {
            const int64_t base = ((int64_t)bh * S_ + t * 32) * D_;
            const float* src = q + base + tid * 8;
            float4 a0 = *reinterpret_cast<const float4*>(src);
            float4 a1 = *reinterpret_cast<const float4*>(src + 4);
            _Float16 ah[8] = { (_Float16)(a0.x * QSCALE), (_Float16)(a0.y * QSCALE),
                               (_Float16)(a0.z * QSCALE), (_Float16)(a0.w * QSCALE),
                               (_Float16)(a1.x * QSCALE), (_Float16)(a1.y * QSCALE),
                               (_Float16)(a1.z * QSCALE), (_Float16)(a1.w * QSCALE) };
            *reinterpret_cast<u32x4*>(qh + base + tid * 8) = *reinterpret_cast<u32x4*>(ah);
        }
        // ---- K pack ----
        {
            const int kk = tid >> 6, lane = tid & 63, hi = lane >> 5, c = lane & 31;
            const float* src = k + ((int64_t)bh * S_ + t * 32 + c) * D_ + kk * 16 + hi * 8;
            float4 a = *reinterpret_cast<const float4*>(src);
            float4 b2 = *reinterpret_cast<const float4*>(src + 4);
            half8 h = { (_Float16)a.x, (_Float16)a.y, (_Float16)a.z, (_Float16)a.w,
                        (_Float16)b2.x, (_Float16)b2.y, (_Float16)b2.z, (_Float16)b2.w };
            half8* dst = reinterpret_cast<half8*>(kh) + (((int64_t)bh * 64 + t) * 4 + kk) * 64 + hi * 32 + c;
            *dst = h;
        }
        // ---- V pack ----
        {
            const int g = tid >> 5, c = tid & 31;
            const int kk = g >> 2, hi = (g >> 1) & 1, db = g & 1;
            const float* src = v + ((int64_t)bh * S_ + t * 32 + kk * 16 + hi * 8) * D_ + c + 32 * db;
            half8 h;
#pragma unroll
            for (int j = 0; j < 8; ++j) h[j] = (_Float16)src[j * D_];
            half8* dst = reinterpret_cast<half8*>(vt) + (((int64_t)bh * 64 + t) * 8 + g) * 32 + c;
            *dst = h;
        }
    } else {
        // ---- mask slice: s in 0..15 -> b = s>>2, q-rows [ (s&3)*512, +512 ) ----
        const int s = y - 64;
        const int b = s >> 2;
        const int q0 = (s & 3) * 512;
        const int lane = tid & 63;
        const int wv = tid >> 6;
        // 512 rows x 32 groups(64 keys) = 16384 groups; 64 blocks x 4 waves x 64 iters
#pragma unroll 4
        for (int i = 0; i < 64; ++i) {
            const int gidx = (t * 4 + wv) * 64 + i;          // 0..16383
            const int qrow = q0 + (gidx >> 5);
            const int u = gidx & 31;
            int mv = mask[(((int64_t)b * S_) + qrow) * S_ + u * 64 + lane];
            unsigned long long bits = __ballot(mv != 0);
            if (lane == 0) {
                const int64_t base = (((int64_t)b * 64 + (qrow >> 5)) * 64) * 32 + (qrow & 31);
                mbT[base + (int64_t)(2 * u) * 32]     = (uint32_t)bits;
                mbT[base + (int64_t)(2 * u + 1) * 32] = (uint32_t)(bits >> 32);
            }
        }
    }
}

// ---------- main attention kernel (FAST path) ----------
// Byte-identical to R18's 518us kernel: packed K/V fragments, per-lane
// softmax (no max-shift), permlane PV frag, XCD decode, coalesced mask,
// pass A K-ring-4, pass B ring-3 with prefetch between PV and stores,
// s_setprio(1) around the MFMA clusters (T5, +5% verified R18).

__global__ __launch_bounds__(256, 2) void attn_fast(
    const _Float16* __restrict__ qh, const _Float16* __restrict__ kh, const _Float16* __restrict__ vt,
    const uint32_t* __restrict__ mbT,
    float* __restrict__ out, float* __restrict__ attn)
{
    const int tid = threadIdx.x;
    const int w = tid >> 6;
    const int lane = tid & 63;
    const int c = lane & 31;
    const int hi = lane >> 5;

    // XCD-aware decode (bijective on 1024 blocks)
    const int fid = blockIdx.x;
    const int xcd = fid & 7;
    const int slot = fid >> 3;
    const int p = xcd + 8 * (slot >> 4);
    const int x = slot & 15;
    const int b = p >> 4;

    const int qw = x * 128 + w * 32;
    const int64_t bh = p;

    half8 aq[4];
    {
        const _Float16* qp = qh + (bh * S_ + qw + c) * D_ + hi * 8;
#pragma unroll
        for (int kk = 0; kk < 4; ++kk)
            aq[kk] = *reinterpret_cast<const half8*>(qp + kk * 16);
    }

    const uint32_t* mT = mbT + (((int64_t)b * 64 + x * 4 + w) * 64) * 32 + c;
    const half8* kbase = reinterpret_cast<const half8*>(kh) + (int64_t)bh * 64 * 4 * 64 + hi * 32 + c;
    const half8* vbase = reinterpret_cast<const half8*>(vt) + (int64_t)bh * 64 * 8 * 32 + c;

    auto LOADK = [&](half8 (&kr)[4], int t) {
        const half8* kp8 = kbase + (int64_t)t * 256;
#pragma unroll
        for (int kk = 0; kk < 4; ++kk) kr[kk] = kp8[kk * 64];
    };
    auto LOADV = [&](half8 (&vr)[4], int t) {
        const half8* vp8 = vbase + (int64_t)t * 256;
        vr[0] = vp8[(hi * 2 + 0) * 32];
        vr[1] = vp8[(hi * 2 + 1) * 32];
        vr[2] = vp8[(4 + hi * 2 + 0) * 32];
        vr[3] = vp8[(4 + hi * 2 + 1) * 32];
    };
    auto QK = [&](const half8 (&kr)[4]) -> f32x16 {
        f32x16 acc;
#pragma unroll
        for (int r = 0; r < 16; ++r) acc[r] = 0.f;
        __builtin_amdgcn_s_setprio(1);
#pragma unroll
        for (int kk = 0; kk < 4; ++kk)
            acc = __builtin_amdgcn_mfma_f32_32x32x16_f16(kr[kk], aq[kk], acc, 0, 0, 0);
        __builtin_amdgcn_s_setprio(0);
        return acc;
    };

    // ================= Pass A: per-lane denominator (K ring-4) =================
    float l = 0.f;
    {
        auto bodyA = [&](const half8 (&kr)[4], uint32_t mwf) -> float {
            f32x16 acc = QK(kr);
            const uint32_t mw = mwf >> (hi * 4);
            float e[16];
#pragma unroll
            for (int r = 0; r < 16; ++r) {
                const bool dead = ((mw >> ((r & 3) + 8 * (r >> 2))) & 1u) == 0u;
                e[r] = __builtin_exp2f(dead ? -1e30f : acc[r]);
            }
#pragma unroll
            for (int st = 1; st < 16; st <<= 1)
#pragma unroll
                for (int i = 0; i < 16; i += 2 * st) e[i] += e[i + st];
            return e[0];
        };

        half8 k0_[4], k1_[4], k2_[4], k3_[4];
        uint32_t m0, m1, m2, m3;
        LOADK(k0_, 0); m0 = mT[0 * 32];
        LOADK(k1_, 1); m1 = mT[1 * 32];
        LOADK(k2_, 2); m2 = mT[2 * 32];
        LOADK(k3_, 3); m3 = mT[3 * 32];
        for (int t = 0; t < 64; t += 4) {
            l += bodyA(k0_, m0); if (t + 4 < 64) { LOADK(k0_, t + 4); m0 = mT[(t + 4) * 32]; }
            l += bodyA(k1_, m1); if (t + 5 < 64) { LOADK(k1_, t + 5); m1 = mT[(t + 5) * 32]; }
            l += bodyA(k2_, m2); if (t + 6 < 64) { LOADK(k2_, t + 6); m2 = mT[(t + 6) * 32]; }
            l += bodyA(k3_, m3); if (t + 7 < 64) { LOADK(k3_, t + 7); m3 = mT[(t + 7) * 32]; }
        }
    }
    const float lt = l + __shfl_xor(l, 32);
    const float rinv = 1.0f / lt;

    // ================= Pass B (K/V/mask ring-3, loads between PV and stores) =================
    f32x16 o0, o1;
#pragma unroll
    for (int r = 0; r < 16; ++r) { o0[r] = 0.f; o1[r] = 0.f; }

    {
        auto stepB = [&](half8 (&K)[4], half8 (&V)[4], uint32_t& m_, int t, int tn) {
            const int k0 = t * 32;
            f32x16 acc = QK(K);
            const uint32_t mw = m_ >> (hi * 4);

            f32x4 pq0, pq1, pq2, pq3;
            uint32_t pk[8];
#pragma unroll
            for (int e2 = 0; e2 < 4; ++e2) {
                bool d0 = ((mw >> (0 + e2)) & 1u) == 0u;
                bool d1 = ((mw >> (8 + e2)) & 1u) == 0u;
                bool d2 = ((mw >> (16 + e2)) & 1u) == 0u;
                bool d3 = ((mw >> (24 + e2)) & 1u) == 0u;
                pq0[e2] = __builtin_exp2f(d0 ? -1e30f : acc[e2]) * rinv;
                pq1[e2] = __builtin_exp2f(d1 ? -1e30f : acc[4 + e2]) * rinv;
                pq2[e2] = __builtin_exp2f(d2 ? -1e30f : acc[8 + e2]) * rinv;
                pq3[e2] = __builtin_exp2f(d3 ? -1e30f : acc[12 + e2]) * rinv;
            }
            pk[0] = __builtin_bit_cast(uint32_t, __builtin_amdgcn_cvt_pkrtz(pq0[0], pq0[1]));
            pk[1] = __builtin_bit_cast(uint32_t, __builtin_amdgcn_cvt_pkrtz(pq0[2], pq0[3]));
            pk[2] = __builtin_bit_cast(uint32_t, __builtin_amdgcn_cvt_pkrtz(pq1[0], pq1[1]));
            pk[3] = __builtin_bit_cast(uint32_t, __builtin_amdgcn_cvt_pkrtz(pq1[2], pq1[3]));
            pk[4] = __builtin_bit_cast(uint32_t, __builtin_amdgcn_cvt_pkrtz(pq2[0], pq2[1]));
            pk[5] = __builtin_bit_cast(uint32_t, __builtin_amdgcn_cvt_pkrtz(pq2[2], pq2[3]));
            pk[6] = __builtin_bit_cast(uint32_t, __builtin_amdgcn_cvt_pkrtz(pq3[0], pq3[1]));
            pk[7] = __builtin_bit_cast(uint32_t, __builtin_amdgcn_cvt_pkrtz(pq3[2], pq3[3]));

            // PV A-frag via permlane (verified path)
            u32x2 rA = __builtin_amdgcn_permlane32_swap(pk[0], pk[2], false, false);
            u32x2 rB = __builtin_amdgcn_permlane32_swap(pk[1], pk[3], false, false);
            u32x2 rC = __builtin_amdgcn_permlane32_swap(pk[4], pk[6], false, false);
            u32x2 rD = __builtin_amdgcn_permlane32_swap(pk[5], pk[7], false, false);
            u32x4 fa0 = { rA[0], rB[0], rA[1], rB[1] };
            u32x4 fa1 = { rC[0], rD[0], rC[1], rD[1] };
            half8 pa0 = __builtin_bit_cast(half8, fa0);
            half8 pa1 = __builtin_bit_cast(half8, fa1);

            __builtin_amdgcn_s_setprio(1);
            o0 = __builtin_amdgcn_mfma_f32_32x32x16_f16(pa0, V[0], o0, 0, 0, 0);
            o1 = __builtin_amdgcn_mfma_f32_32x32x16_f16(pa0, V[1], o1, 0, 0, 0);
            o0 = __builtin_amdgcn_mfma_f32_32x32x16_f16(pa1, V[2], o0, 0, 0, 0);
            o1 = __builtin_amdgcn_mfma_f32_32x32x16_f16(pa1, V[3], o1, 0, 0, 0);
            __builtin_amdgcn_s_setprio(0);

            // prefetch tile tn BEFORE this tile's stores
            if (tn < 64) { LOADK(K, tn); LOADV(V, tn); m_ = mT[tn * 32]; }

            float* arow = attn + (bh * S_ + qw + c) * (int64_t)S_ + k0 + 4 * hi;
            *reinterpret_cast<f32x4*>(arow) = pq0;
            *reinterpret_cast<f32x4*>(arow + 8) = pq1;
            *reinterpret_cast<f32x4*>(arow + 16) = pq2;
            *reinterpret_cast<f32x4*>(arow + 24) = pq3;
        };

        half8 Ka[4], Kb[4], Kc[4], Va[4], Vb[4], Vc[4];
        uint32_t ma, mb_, mc;
        LOADK(Ka, 0); LOADV(Va, 0); ma = mT[0 * 32];
        LOADK(Kb, 1); LOADV(Vb, 1); mb_ = mT[1 * 32];
        LOADK(Kc, 2); LOADV(Vc, 2); mc = mT[2 * 32];
        for (int t = 0; t < 63; t += 3) {
            stepB(Ka, Va, ma, t, t + 3);
            stepB(Kb, Vb, mb_, t + 1, t + 4);
            stepB(Kc, Vc, mc, t + 2, t + 5);
        }
        stepB(Ka, Va, ma, 63, 64);
    }

    // out store
#pragma unroll
    for (int r = 0; r < 16; ++r) {
        const int row = (r & 3) + 8 * (r >> 2) + 4 * hi;
        float* op = out + (bh * S_ + qw + row) * D_;
        op[c] = o0[r];
        op[c + 32] = o1[r];
    }
}

// ---------- fallback: single-kernel fp32 path (no workspace) ----------
__global__ __launch_bounds__(256, 2) void attn_slow(
    const float* __restrict__ qf, const float* __restrict__ kf, const float* __restrict__ vf,
    const int* __restrict__ maskI, float* __restrict__ out, float* __restrict__ attn)
{
    const int tid = threadIdx.x;
    const int w = tid >> 6;
    const int lane = tid & 63;
    const int c = lane & 31;
    const int hi = lane >> 5;
    const int fid = blockIdx.x;
    const int p = fid & 63;
    const int x = fid >> 6;
    const int b = p >> 4;
    const int qw = x * 128 + w * 32;
    const int64_t bh = p;
    const int64_t qrow = (int64_t)b * S_ + qw + c;

    half8 aq[4];
    {
        const float* qp = qf + (bh * S_ + qw + c) * D_ + hi * 8;
#pragma unroll
        for (int kk = 0; kk < 4; ++kk)
#pragma unroll
            for (int j = 0; j < 8; ++j)
                aq[kk][j] = (_Float16)(qp[kk * 16 + j] * QSCALE);
    }

    float l = 0.f;
    for (int t = 0; t < 64; ++t) {
        const int k0 = t * 32;
        f32x16 acc;
#pragma unroll
        for (int r = 0; r < 16; ++r) acc[r] = 0.f;
        const float* kp = kf + (bh * S_ + k0 + c) * D_ + hi * 8;
#pragma unroll
        for (int kk = 0; kk < 4; ++kk) {
            half8 bk;
#pragma unroll
            for (int j = 0; j < 8; ++j) bk[j] = (_Float16)kp[kk * 16 + j];
            acc = __builtin_amdgcn_mfma_f32_32x32x16_f16(bk, aq[kk], acc, 0, 0, 0);
        }
        float e[16];
#pragma unroll
        for (int r = 0; r < 16; ++r) {
            const int key = k0 + (r & 3) + 8 * (r >> 2) + 4 * hi;
            const bool dead = maskI[qrow * S_ + key] == 0;
            e[r] = __builtin_exp2f(dead ? -1e30f : acc[r]);
        }
#pragma unroll
        for (int st = 1; st < 16; st <<= 1)
#pragma unroll
            for (int i = 0; i < 16; i += 2 * st) e[i] += e[i + st];
        l += e[0];
    }
    const float lt = l + __shfl_xor(l, 32);
    const float rinv = 1.0f / lt;

    f32x16 o0, o1;
#pragma unroll
    for (int r = 0; r < 16; ++r) { o0[r] = 0.f; o1[r] = 0.f; }

    for (int t = 0; t < 64; ++t) {
        const int k0 = t * 32;
        f32x16 acc;
#pragma unroll
        for (int r = 0; r < 16; ++r) acc[r] = 0.f;
        const float* kp = kf + (bh * S_ + k0 + c) * D_ + hi * 8;
#pragma unroll
        for (int kk = 0; kk < 4; ++kk) {
            half8 bk;
#pragma unroll
            for (int j = 0; j < 8; ++j) bk[j] = (_Float16)kp[kk * 16 + j];
            acc = __builtin_amdgcn_mfma_f32_32x32x16_f16(bk, aq[kk], acc, 0, 0, 0);
        }
        float* arow = attn + (bh * S_ + qw + c) * (int64_t)S_ + k0 + 4 * hi;
        uint32_t pk[8];
#pragma unroll
        for (int g4 = 0; g4 < 4; ++g4) {
            f32x4 pq;
#pragma unroll
            for (int e2 = 0; e2 < 4; ++e2) {
                const int key = k0 + e2 + 8 * g4 + 4 * hi;
                const bool dead = maskI[qrow * S_ + key] == 0;
                pq[e2] = __builtin_exp2f(dead ? -1e30f : acc[4 * g4 + e2]) * rinv;
            }
            *reinterpret_cast<f32x4*>(arow + 8 * g4) = pq;
            pk[2 * g4]     = __builtin_bit_cast(uint32_t, __builtin_amdgcn_cvt_pkrtz(pq[0], pq[1]));
            pk[2 * g4 + 1] = __builtin_bit_cast(uint32_t, __builtin_amdgcn_cvt_pkrtz(pq[2], pq[3]));
        }
        u32x2 rA = __builtin_amdgcn_permlane32_swap(pk[0], pk[2], false, false);
        u32x2 rB = __builtin_amdgcn_permlane32_swap(pk[1], pk[3], false, false);
        u32x2 rC = __builtin_amdgcn_permlane32_swap(pk[4], pk[6], false, false);
        u32x2 rD = __builtin_amdgcn_permlane32_swap(pk[5], pk[7], false, false);
        u32x4 fa0 = { rA[0], rB[0], rA[1], rB[1] };
        u32x4 fa1 = { rC[0], rD[0], rC[1], rD[1] };
        half8 pa0 = __builtin_bit_cast(half8, fa0);
        half8 pa1 = __builtin_bit_cast(half8, fa1);

        half8 bv00, bv01, bv10, bv11;
        const float* vp0 = vf + (bh * S_ + k0 + hi * 8) * D_ + c;
        const float* vp1 = vp0 + 16 * D_;
#pragma unroll
        for (int j = 0; j < 8; ++j) {
            bv00[j] = (_Float16)vp0[j * D_];
            bv01[j] = (_Float16)vp0[j * D_ + 32];
            bv10[j] = (_Float16)vp1[j * D_];
            bv11[j] = (_Float16)vp1[j * D_ + 32];
        }
        o0 = __builtin_amdgcn_mfma_f32_32x32x16_f16(pa0, bv00, o0, 0, 0, 0);
        o1 = __builtin_amdgcn_mfma_f32_32x32x16_f16(pa0, bv01, o1, 0, 0, 0);
        o0 = __builtin_amdgcn_mfma_f32_32x32x16_f16(pa1, bv10, o0, 0, 0, 0);
        o1 = __builtin_amdgcn_mfma_f32_32x32x16_f16(pa1, bv11, o1, 0, 0, 0);
    }

#pragma unroll
    for (int r = 0; r < 16; ++r) {
        const int row = (r & 3) + 8 * (r >> 2) + 4 * hi;
        float* op = out + (bh * S_ + qw + row) * D_;
        op[c] = o0[r];
        op[c + 32] = o1[r];
    }
}

// ---------- launch ----------
extern "C" void kernel_launch(void* const* d_in, const int* in_sizes, int n_in,
                              void* d_out, int out_size, void* d_ws, size_t ws_size,
                              hipStream_t stream) {
    const float* q = (const float*)d_in[0];
    const float* k = (const float*)d_in[1];
    const float* v = (const float*)d_in[2];
    const int* mask = (const int*)d_in[3];
    float* out = (float*)d_out;
    float* attn = out + (int64_t)B_ * H_ * S_ * D_;

    const size_t nElem = (size_t)B_ * H_ * S_ * D_;           // 8388608
    const size_t maskWords = (size_t)B_ * S_ * (S_ / 32);     // 524288
    const size_t need = nElem * 2 * 3 + maskWords * 4;        // 52,428,800 B

    const int nblk = B_ * H_ * (S_ / 128);                    // 1024
    if (d_ws != nullptr && ws_size >= need) {
        _Float16* qh = (_Float16*)d_ws;
        _Float16* kh = qh + nElem;
        _Float16* vt = kh + nElem;
        uint32_t* mbT = (uint32_t*)(vt + nElem);
        pack_all<<<dim3(64, 80), 256, 0, stream>>>(q, k, v, mask, qh, kh, vt, mbT);
        attn_fast<<<nblk, 256, 0, stream>>>(qh, kh, vt, mbT, out, attn);
    } else {
        attn_slow<<<nblk, 256, 0, stream>>>(q, k, v, mask, out, attn);
    }
}

// Round 20
// 515.748 us; speedup vs baseline: 1.0565x; 1.0565x over previous
//
#include <hip/hip_runtime.h>
#include <cstdint>

#define B_ 4
#define H_ 16
#define S_ 2048
#define D_ 64

// fold temperature (1/8) and log2(e) into q so exp(x) == exp2(scaled dot)
#define QSCALE (0.125f * 1.44269504088896f)

typedef _Float16 half8 __attribute__((ext_vector_type(8)));
typedef float f32x4 __attribute__((ext_vector_type(4)));
typedef float f32x16 __attribute__((ext_vector_type(16)));
typedef uint32_t u32x2 __attribute__((ext_vector_type(2)));
typedef uint32_t u32x4 __attribute__((ext_vector_type(4)));

// ---------- pre-kernels (separate launches: fused version regressed, R19) ----------

__global__ void cvt_q_kernel(const float* __restrict__ q, _Float16* __restrict__ qh) {
    const int64_t N = (int64_t)B_ * H_ * S_ * D_;
    const int64_t step = (int64_t)gridDim.x * blockDim.x * 4;
    for (int64_t i = ((int64_t)blockIdx.x * blockDim.x + threadIdx.x) * 4; i < N; i += step) {
        float4 a = *reinterpret_cast<const float4*>(q + i);
        _Float16 ah[4] = { (_Float16)(a.x * QSCALE), (_Float16)(a.y * QSCALE),
                           (_Float16)(a.z * QSCALE), (_Float16)(a.w * QSCALE) };
        *reinterpret_cast<u32x2*>(qh + i) = *reinterpret_cast<u32x2*>(ah);
    }
}

// K -> FRAGMENT layout: half8 slot [((bh*64+t)*4+kk)*64 + hi*32 + c]
__global__ void pack_k_kernel(const float* __restrict__ k, _Float16* __restrict__ kh) {
    const int bh = blockIdx.y;
    const int t = blockIdx.x;
    const int tid = threadIdx.x;
    const int kk = tid >> 6, lane = tid & 63, hi = lane >> 5, c = lane & 31;
    const float* src = k + ((int64_t)bh * S_ + t * 32 + c) * D_ + kk * 16 + hi * 8;
    float4 a = *reinterpret_cast<const float4*>(src);
    float4 b2 = *reinterpret_cast<const float4*>(src + 4);
    half8 h = { (_Float16)a.x, (_Float16)a.y, (_Float16)a.z, (_Float16)a.w,
                (_Float16)b2.x, (_Float16)b2.y, (_Float16)b2.z, (_Float16)b2.w };
    half8* dst = reinterpret_cast<half8*>(kh) + (((int64_t)bh * 64 + t) * 4 + kk) * 64 + hi * 32 + c;
    *dst = h;
}

// V -> FRAGMENT layout: half8 slot [((bh*64+t)*8 + g)*32 + c], g = kk*4+hi*2+db
__global__ void pack_v_kernel(const float* __restrict__ v, _Float16* __restrict__ vt) {
    const int bh = blockIdx.y;
    const int t = blockIdx.x;
    const int tid = threadIdx.x;
    const int g = tid >> 5, c = tid & 31;
    const int kk = g >> 2, hi = (g >> 1) & 1, db = g & 1;
    const float* src = v + ((int64_t)bh * S_ + t * 32 + kk * 16 + hi * 8) * D_ + c + 32 * db;
    half8 h;
#pragma unroll
    for (int j = 0; j < 8; ++j) h[j] = (_Float16)src[j * D_];
    half8* dst = reinterpret_cast<half8*>(vt) + (((int64_t)bh * 64 + t) * 8 + g) * 32 + c;
    *dst = h;
}

// mask -> QUERY-TILE-MAJOR bitmap: word [((b*64 + q/32)*64 + t)*32 + q%32]
__global__ void pack_mask_kernel(const int* __restrict__ mask, uint32_t* __restrict__ mbT) {
    const int64_t groups = (int64_t)B_ * S_ * S_ / 64;   // 64 keys per group
    const int lane = threadIdx.x & 63;
    const int64_t wstep = ((int64_t)gridDim.x * blockDim.x) >> 6;
    for (int64_t g = ((int64_t)blockIdx.x * blockDim.x + threadIdx.x) >> 6; g < groups; g += wstep) {
        int mv = mask[g * 64 + lane];
        unsigned long long bits = __ballot(mv != 0);
        if (lane == 0) {
            const int u = (int)(g & 31);
            const int64_t bq = g >> 5;
            const int q = (int)(bq & (S_ - 1));
            const int b = (int)(bq >> 11);
            const int64_t base = (((int64_t)b * 64 + (q >> 5)) * 64) * 32 + (q & 31);
            mbT[base + (int64_t)(2 * u) * 32]     = (uint32_t)bits;
            mbT[base + (int64_t)(2 * u + 1) * 32] = (uint32_t)(bits >> 32);
        }
    }
}

// ---------- main attention kernel (FAST path) ----------
// Best-known structure (R18, 518us): packed K/V fragments, per-lane softmax
// (no max-shift), permlane PV frag, XCD decode, coalesced mask, pass A
// K-ring-4, pass B ring-3 with next-tile prefetch issued BETWEEN the PV
// MFMAs and the attn stores (in-order vmcnt keeps stores off the QK path),
// s_setprio(1) around the MFMA clusters (T5, +5% verified R18).

__global__ __launch_bounds__(256, 2) void attn_fast(
    const _Float16* __restrict__ qh, const _Float16* __restrict__ kh, const _Float16* __restrict__ vt,
    const uint32_t* __restrict__ mbT,
    float* __restrict__ out, float* __restrict__ attn)
{
    const int tid = threadIdx.x;
    const int w = tid >> 6;
    const int lane = tid & 63;
    const int c = lane & 31;
    const int hi = lane >> 5;

    // XCD-aware decode (bijective on 1024 blocks)
    const int fid = blockIdx.x;
    const int xcd = fid & 7;
    const int slot = fid >> 3;
    const int p = xcd + 8 * (slot >> 4);
    const int x = slot & 15;
    const int b = p >> 4;

    const int qw = x * 128 + w * 32;
    const int64_t bh = p;

    half8 aq[4];
    {
        const _Float16* qp = qh + (bh * S_ + qw + c) * D_ + hi * 8;
#pragma unroll
        for (int kk = 0; kk < 4; ++kk)
            aq[kk] = *reinterpret_cast<const half8*>(qp + kk * 16);
    }

    const uint32_t* mT = mbT + (((int64_t)b * 64 + x * 4 + w) * 64) * 32 + c;
    const half8* kbase = reinterpret_cast<const half8*>(kh) + (int64_t)bh * 64 * 4 * 64 + hi * 32 + c;
    const half8* vbase = reinterpret_cast<const half8*>(vt) + (int64_t)bh * 64 * 8 * 32 + c;

    auto LOADK = [&](half8 (&kr)[4], int t) {
        const half8* kp8 = kbase + (int64_t)t * 256;
#pragma unroll
        for (int kk = 0; kk < 4; ++kk) kr[kk] = kp8[kk * 64];
    };
    auto LOADV = [&](half8 (&vr)[4], int t) {
        const half8* vp8 = vbase + (int64_t)t * 256;
        vr[0] = vp8[(hi * 2 + 0) * 32];
        vr[1] = vp8[(hi * 2 + 1) * 32];
        vr[2] = vp8[(4 + hi * 2 + 0) * 32];
        vr[3] = vp8[(4 + hi * 2 + 1) * 32];
    };
    auto QK = [&](const half8 (&kr)[4]) -> f32x16 {
        f32x16 acc;
#pragma unroll
        for (int r = 0; r < 16; ++r) acc[r] = 0.f;
        __builtin_amdgcn_s_setprio(1);
#pragma unroll
        for (int kk = 0; kk < 4; ++kk)
            acc = __builtin_amdgcn_mfma_f32_32x32x16_f16(kr[kk], aq[kk], acc, 0, 0, 0);
        __builtin_amdgcn_s_setprio(0);
        return acc;
    };

    // ================= Pass A: per-lane denominator (K ring-4) =================
    float l = 0.f;
    {
        auto bodyA = [&](const half8 (&kr)[4], uint32_t mwf) -> float {
            f32x16 acc = QK(kr);
            const uint32_t mw = mwf >> (hi * 4);
            float e[16];
#pragma unroll
            for (int r = 0; r < 16; ++r) {
                const bool dead = ((mw >> ((r & 3) + 8 * (r >> 2))) & 1u) == 0u;
                e[r] = __builtin_exp2f(dead ? -1e30f : acc[r]);
            }
#pragma unroll
            for (int st = 1; st < 16; st <<= 1)
#pragma unroll
                for (int i = 0; i < 16; i += 2 * st) e[i] += e[i + st];
            return e[0];
        };

        half8 k0_[4], k1_[4], k2_[4], k3_[4];
        uint32_t m0, m1, m2, m3;
        LOADK(k0_, 0); m0 = mT[0 * 32];
        LOADK(k1_, 1); m1 = mT[1 * 32];
        LOADK(k2_, 2); m2 = mT[2 * 32];
        LOADK(k3_, 3); m3 = mT[3 * 32];
        for (int t = 0; t < 64; t += 4) {
            l += bodyA(k0_, m0); if (t + 4 < 64) { LOADK(k0_, t + 4); m0 = mT[(t + 4) * 32]; }
            l += bodyA(k1_, m1); if (t + 5 < 64) { LOADK(k1_, t + 5); m1 = mT[(t + 5) * 32]; }
            l += bodyA(k2_, m2); if (t + 6 < 64) { LOADK(k2_, t + 6); m2 = mT[(t + 6) * 32]; }
            l += bodyA(k3_, m3); if (t + 7 < 64) { LOADK(k3_, t + 7); m3 = mT[(t + 7) * 32]; }
        }
    }
    const float lt = l + __shfl_xor(l, 32);
    const float rinv = 1.0f / lt;

    // ================= Pass B (K/V/mask ring-3, loads between PV and stores) =================
    f32x16 o0, o1;
#pragma unroll
    for (int r = 0; r < 16; ++r) { o0[r] = 0.f; o1[r] = 0.f; }

    {
        auto stepB = [&](half8 (&K)[4], half8 (&V)[4], uint32_t& m_, int t, int tn) {
            const int k0 = t * 32;
            f32x16 acc = QK(K);
            const uint32_t mw = m_ >> (hi * 4);

            f32x4 pq0, pq1, pq2, pq3;
            uint32_t pk[8];
#pragma unroll
            for (int e2 = 0; e2 < 4; ++e2) {
                bool d0 = ((mw >> (0 + e2)) & 1u) == 0u;
                bool d1 = ((mw >> (8 + e2)) & 1u) == 0u;
                bool d2 = ((mw >> (16 + e2)) & 1u) == 0u;
                bool d3 = ((mw >> (24 + e2)) & 1u) == 0u;
                pq0[e2] = __builtin_exp2f(d0 ? -1e30f : acc[e2]) * rinv;
                pq1[e2] = __builtin_exp2f(d1 ? -1e30f : acc[4 + e2]) * rinv;
                pq2[e2] = __builtin_exp2f(d2 ? -1e30f : acc[8 + e2]) * rinv;
                pq3[e2] = __builtin_exp2f(d3 ? -1e30f : acc[12 + e2]) * rinv;
            }
            pk[0] = __builtin_bit_cast(uint32_t, __builtin_amdgcn_cvt_pkrtz(pq0[0], pq0[1]));
            pk[1] = __builtin_bit_cast(uint32_t, __builtin_amdgcn_cvt_pkrtz(pq0[2], pq0[3]));
            pk[2] = __builtin_bit_cast(uint32_t, __builtin_amdgcn_cvt_pkrtz(pq1[0], pq1[1]));
            pk[3] = __builtin_bit_cast(uint32_t, __builtin_amdgcn_cvt_pkrtz(pq1[2], pq1[3]));
            pk[4] = __builtin_bit_cast(uint32_t, __builtin_amdgcn_cvt_pkrtz(pq2[0], pq2[1]));
            pk[5] = __builtin_bit_cast(uint32_t, __builtin_amdgcn_cvt_pkrtz(pq2[2], pq2[3]));
            pk[6] = __builtin_bit_cast(uint32_t, __builtin_amdgcn_cvt_pkrtz(pq3[0], pq3[1]));
            pk[7] = __builtin_bit_cast(uint32_t, __builtin_amdgcn_cvt_pkrtz(pq3[2], pq3[3]));

            // PV A-frag via permlane (verified path)
            u32x2 rA = __builtin_amdgcn_permlane32_swap(pk[0], pk[2], false, false);
            u32x2 rB = __builtin_amdgcn_permlane32_swap(pk[1], pk[3], false, false);
            u32x2 rC = __builtin_amdgcn_permlane32_swap(pk[4], pk[6], false, false);
            u32x2 rD = __builtin_amdgcn_permlane32_swap(pk[5], pk[7], false, false);
            u32x4 fa0 = { rA[0], rB[0], rA[1], rB[1] };
            u32x4 fa1 = { rC[0], rD[0], rC[1], rD[1] };
            half8 pa0 = __builtin_bit_cast(half8, fa0);
            half8 pa1 = __builtin_bit_cast(half8, fa1);

            __builtin_amdgcn_s_setprio(1);
            o0 = __builtin_amdgcn_mfma_f32_32x32x16_f16(pa0, V[0], o0, 0, 0, 0);
            o1 = __builtin_amdgcn_mfma_f32_32x32x16_f16(pa0, V[1], o1, 0, 0, 0);
            o0 = __builtin_amdgcn_mfma_f32_32x32x16_f16(pa1, V[2], o0, 0, 0, 0);
            o1 = __builtin_amdgcn_mfma_f32_32x32x16_f16(pa1, V[3], o1, 0, 0, 0);
            __builtin_amdgcn_s_setprio(0);

            // prefetch tile tn BEFORE this tile's stores
            if (tn < 64) { LOADK(K, tn); LOADV(V, tn); m_ = mT[tn * 32]; }

            float* arow = attn + (bh * S_ + qw + c) * (int64_t)S_ + k0 + 4 * hi;
            *reinterpret_cast<f32x4*>(arow) = pq0;
            *reinterpret_cast<f32x4*>(arow + 8) = pq1;
            *reinterpret_cast<f32x4*>(arow + 16) = pq2;
            *reinterpret_cast<f32x4*>(arow + 24) = pq3;
        };

        half8 Ka[4], Kb[4], Kc[4], Va[4], Vb[4], Vc[4];
        uint32_t ma, mb_, mc;
        LOADK(Ka, 0); LOADV(Va, 0); ma = mT[0 * 32];
        LOADK(Kb, 1); LOADV(Vb, 1); mb_ = mT[1 * 32];
        LOADK(Kc, 2); LOADV(Vc, 2); mc = mT[2 * 32];
        for (int t = 0; t < 63; t += 3) {
            stepB(Ka, Va, ma, t, t + 3);
            stepB(Kb, Vb, mb_, t + 1, t + 4);
            stepB(Kc, Vc, mc, t + 2, t + 5);
        }
        stepB(Ka, Va, ma, 63, 64);
    }

    // out store
#pragma unroll
    for (int r = 0; r < 16; ++r) {
        const int row = (r & 3) + 8 * (r >> 2) + 4 * hi;
        float* op = out + (bh * S_ + qw + row) * D_;
        op[c] = o0[r];
        op[c + 32] = o1[r];
    }
}

// ---------- fallback: single-kernel fp32 path (no workspace) ----------
__global__ __launch_bounds__(256, 2) void attn_slow(
    const float* __restrict__ qf, const float* __restrict__ kf, const float* __restrict__ vf,
    const int* __restrict__ maskI, float* __restrict__ out, float* __restrict__ attn)
{
    const int tid = threadIdx.x;
    const int w = tid >> 6;
    const int lane = tid & 63;
    const int c = lane & 31;
    const int hi = lane >> 5;
    const int fid = blockIdx.x;
    const int p = fid & 63;
    const int x = fid >> 6;
    const int b = p >> 4;
    const int qw = x * 128 + w * 32;
    const int64_t bh = p;
    const int64_t qrow = (int64_t)b * S_ + qw + c;

    half8 aq[4];
    {
        const float* qp = qf + (bh * S_ + qw + c) * D_ + hi * 8;
#pragma unroll
        for (int kk = 0; kk < 4; ++kk)
#pragma unroll
            for (int j = 0; j < 8; ++j)
                aq[kk][j] = (_Float16)(qp[kk * 16 + j] * QSCALE);
    }

    float l = 0.f;
    for (int t = 0; t < 64; ++t) {
        const int k0 = t * 32;
        f32x16 acc;
#pragma unroll
        for (int r = 0; r < 16; ++r) acc[r] = 0.f;
        const float* kp = kf + (bh * S_ + k0 + c) * D_ + hi * 8;
#pragma unroll
        for (int kk = 0; kk < 4; ++kk) {
            half8 bk;
#pragma unroll
            for (int j = 0; j < 8; ++j) bk[j] = (_Float16)kp[kk * 16 + j];
            acc = __builtin_amdgcn_mfma_f32_32x32x16_f16(bk, aq[kk], acc, 0, 0, 0);
        }
        float e[16];
#pragma unroll
        for (int r = 0; r < 16; ++r) {
            const int key = k0 + (r & 3) + 8 * (r >> 2) + 4 * hi;
            const bool dead = maskI[qrow * S_ + key] == 0;
            e[r] = __builtin_exp2f(dead ? -1e30f : acc[r]);
        }
#pragma unroll
        for (int st = 1; st < 16; st <<= 1)
#pragma unroll
            for (int i = 0; i < 16; i += 2 * st) e[i] += e[i + st];
        l += e[0];
    }
    const float lt = l + __shfl_xor(l, 32);
    const float rinv = 1.0f / lt;

    f32x16 o0, o1;
#pragma unroll
    for (int r = 0; r < 16; ++r) { o0[r] = 0.f; o1[r] = 0.f; }

    for (int t = 0; t < 64; ++t) {
        const int k0 = t * 32;
        f32x16 acc;
#pragma unroll
        for (int r = 0; r < 16; ++r) acc[r] = 0.f;
        const float* kp = kf + (bh * S_ + k0 + c) * D_ + hi * 8;
#pragma unroll
        for (int kk = 0; kk < 4; ++kk) {
            half8 bk;
#pragma unroll
            for (int j = 0; j < 8; ++j) bk[j] = (_Float16)kp[kk * 16 + j];
            acc = __builtin_amdgcn_mfma_f32_32x32x16_f16(bk, aq[kk], acc, 0, 0, 0);
        }
        float* arow = attn + (bh * S_ + qw + c) * (int64_t)S_ + k0 + 4 * hi;
        uint32_t pk[8];
#pragma unroll
        for (int g4 = 0; g4 < 4; ++g4) {
            f32x4 pq;
#pragma unroll
            for (int e2 = 0; e2 < 4; ++e2) {
                const int key = k0 + e2 + 8 * g4 + 4 * hi;
                const bool dead = maskI[qrow * S_ + key] == 0;
                pq[e2] = __builtin_exp2f(dead ? -1e30f : acc[4 * g4 + e2]) * rinv;
            }
            *reinterpret_cast<f32x4*>(arow + 8 * g4) = pq;
            pk[2 * g4]     = __builtin_bit_cast(uint32_t, __builtin_amdgcn_cvt_pkrtz(pq[0], pq[1]));
            pk[2 * g4 + 1] = __builtin_bit_cast(uint32_t, __builtin_amdgcn_cvt_pkrtz(pq[2], pq[3]));
        }
        u32x2 rA = __builtin_amdgcn_permlane32_swap(pk[0], pk[2], false, false);
        u32x2 rB = __builtin_amdgcn_permlane32_swap(pk[1], pk[3], false, false);
        u32x2 rC = __builtin_amdgcn_permlane32_swap(pk[4], pk[6], false, false);
        u32x2 rD = __builtin_amdgcn_permlane32_swap(pk[5], pk[7], false, false);
        u32x4 fa0 = { rA[0], rB[0], rA[1], rB[1] };
        u32x4 fa1 = { rC[0], rD[0], rC[1], rD[1] };
        half8 pa0 = __builtin_bit_cast(half8, fa0);
        half8 pa1 = __builtin_bit_cast(half8, fa1);

        half8 bv00, bv01, bv10, bv11;
        const float* vp0 = vf + (bh * S_ + k0 + hi * 8) * D_ + c;
        const float* vp1 = vp0 + 16 * D_;
#pragma unroll
        for (int j = 0; j < 8; ++j) {
            bv00[j] = (_Float16)vp0[j * D_];
            bv01[j] = (_Float16)vp0[j * D_ + 32];
            bv10[j] = (_Float16)vp1[j * D_];
            bv11[j] = (_Float16)vp1[j * D_ + 32];
        }
        o0 = __builtin_amdgcn_mfma_f32_32x32x16_f16(pa0, bv00, o0, 0, 0, 0);
        o1 = __builtin_amdgcn_mfma_f32_32x32x16_f16(pa0, bv01, o1, 0, 0, 0);
        o0 = __builtin_amdgcn_mfma_f32_32x32x16_f16(pa1, bv10, o0, 0, 0, 0);
        o1 = __builtin_amdgcn_mfma_f32_32x32x16_f16(pa1, bv11, o1, 0, 0, 0);
    }

#pragma unroll
    for (int r = 0; r < 16; ++r) {
        const int row = (r & 3) + 8 * (r >> 2) + 4 * hi;
        float* op = out + (bh * S_ + qw + row) * D_;
        op[c] = o0[r];
        op[c + 32] = o1[r];
    }
}

// ---------- launch ----------
extern "C" void kernel_launch(void* const* d_in, const int* in_sizes, int n_in,
                              void* d_out, int out_size, void* d_ws, size_t ws_size,
                              hipStream_t stream) {
    const float* q = (const float*)d_in[0];
    const float* k = (const float*)d_in[1];
    const float* v = (const float*)d_in[2];
    const int* mask = (const int*)d_in[3];
    float* out = (float*)d_out;
    float* attn = out + (int64_t)B_ * H_ * S_ * D_;

    const size_t nElem = (size_t)B_ * H_ * S_ * D_;           // 8388608
    const size_t maskWords = (size_t)B_ * S_ * (S_ / 32);     // 524288
    const size_t need = nElem * 2 * 3 + maskWords * 4;        // 52,428,800 B

    const int nblk = B_ * H_ * (S_ / 128);                    // 1024
    if (d_ws != nullptr && ws_size >= need) {
        _Float16* qh = (_Float16*)d_ws;
        _Float16* kh = qh + nElem;
        _Float16* vt = kh + nElem;
        uint32_t* mbT = (uint32_t*)(vt + nElem);
        cvt_q_kernel<<<1024, 256, 0, stream>>>(q, qh);
        pack_k_kernel<<<dim3(S_ / 32, B_ * H_), 256, 0, stream>>>(k, kh);
        pack_v_kernel<<<dim3(S_ / 32, B_ * H_), 256, 0, stream>>>(v, vt);
        pack_mask_kernel<<<2048, 256, 0, stream>>>(mask, mbT);
        attn_fast<<<nblk, 256, 0, stream>>>(qh, kh, vt, mbT, out, attn);
    } else {
        attn_slow<<<nblk, 256, 0, stream>>>(q, k, v, mask, out, attn);
    }
}